// Round 13
// baseline (499.861 us; speedup 1.0000x reference)
//
#include <hip/hip_runtime.h>
#include <math.h>

#define N_NODES 50000
#define E_RAW 800000
#define E_TOT 850000
#define NEG_SLOPE 0.2f
#define NBLK ((N_NODES + 1023) / 1024)
#define G1_BLOCKS ((N_NODES + 31) / 32)          // 1563 gemm1 blocks (MT=32, 256 thr)
#define G2_BLOCKS ((E_TOT / 4 + 255) / 256)      // 830 deg blocks
#define ILV (2 * G2_BLOCKS)                      // interleave window: odd = deg

__device__ __forceinline__ float lrelu(float a) { return a > 0.f ? a : NEG_SLOPE * a; }

__device__ __forceinline__ unsigned f2bf(float f) {
    unsigned u = __float_as_uint(f);
    return (u + 0x7fff + ((u >> 16) & 1)) >> 16;
}
__device__ __forceinline__ unsigned pack2(float a, float b) {
    return f2bf(a) | (f2bf(b) << 16);
}
__device__ __forceinline__ float bflo(unsigned p) { return __uint_as_float(p << 16); }
__device__ __forceinline__ float bfhi(unsigned p) { return __uint_as_float(p & 0xffff0000u); }

// ---------------- FUSED: gemm1 || deg_rank, interleaved block mapping ----------------
// gemm1: 256 thr, MT=32, 8 groups x 4 rows, 4 cols/thread. deg: 4 edges/thread atomics.
__global__ void k_gemm1_deg(const float* __restrict__ A, const float* __restrict__ B,
                            const float* __restrict__ aux, uint2* __restrict__ C,
                            float* __restrict__ es, float* __restrict__ ed,
                            const int* __restrict__ ei, int* __restrict__ deg,
                            unsigned short* __restrict__ rank) {
    constexpr int K = 128, MT = 32;
    __shared__ float As[MT * K];   // 16 KB
    int bid = blockIdx.x;
    bool isDeg = (bid < ILV) && (bid & 1);
    if (isDeg) {
        int t = (bid >> 1) * 256 + threadIdx.x;
        int e0 = 4 * t;
        if (e0 >= E_TOT) return;
        int col[4];
        if (e0 + 3 < E_RAW) {
            int4 c4 = ((const int4*)(ei + E_RAW))[t];
            col[0] = c4.x; col[1] = c4.y; col[2] = c4.z; col[3] = c4.w;
        } else {
#pragma unroll
            for (int i = 0; i < 4; ++i) {
                int e = e0 + i;
                col[i] = (e < E_RAW) ? ei[E_RAW + e] : (e - E_RAW);
            }
        }
        unsigned short rk[4];
#pragma unroll
        for (int i = 0; i < 4; ++i)
            rk[i] = (e0 + i < E_TOT) ? (unsigned short)atomicAdd(&deg[col[i]], 1) : (unsigned short)0;
        if (e0 + 3 < E_TOT) {
            ushort4 v; v.x = rk[0]; v.y = rk[1]; v.z = rk[2]; v.w = rk[3];
            ((ushort4*)rank)[t] = v;
        } else {
#pragma unroll
            for (int i = 0; i < 4; ++i)
                if (e0 + i < E_TOT) rank[e0 + i] = rk[i];
        }
        return;
    }
    int gemmIdx = (bid < ILV) ? (bid >> 1) : (bid - G2_BLOCKS);
    int t = threadIdx.x, g = t >> 5, l = t & 31;   // 8 groups x 32 lanes
    int m0 = gemmIdx * MT;
    int rows = min(MT, N_NODES - m0);
    const float4* A4 = (const float4*)(A + (size_t)m0 * K);
    float4* S4 = (float4*)As;
    for (int i = t; i < rows * (K / 4); i += 256) S4[i] = A4[i];
    __syncthreads();
    float acc[4][4];
#pragma unroll
    for (int r = 0; r < 4; ++r)
#pragma unroll
        for (int c = 0; c < 4; ++c) acc[r][c] = 0.f;
    const float4* B4 = (const float4*)B;   // row k = 32 float4
    for (int kk = 0; kk < K / 4; ++kk) {
        float4 b0 = B4[(4 * kk + 0) * 32 + l];
        float4 b1 = B4[(4 * kk + 1) * 32 + l];
        float4 b2 = B4[(4 * kk + 2) * 32 + l];
        float4 b3 = B4[(4 * kk + 3) * 32 + l];
#pragma unroll
        for (int r = 0; r < 4; ++r) {
            float4 a = ((const float4*)(As + (g * 4 + r) * K))[kk];
            acc[r][0] = fmaf(a.x, b0.x, fmaf(a.y, b1.x, fmaf(a.z, b2.x, fmaf(a.w, b3.x, acc[r][0]))));
            acc[r][1] = fmaf(a.x, b0.y, fmaf(a.y, b1.y, fmaf(a.z, b2.y, fmaf(a.w, b3.y, acc[r][1]))));
            acc[r][2] = fmaf(a.x, b0.z, fmaf(a.y, b1.z, fmaf(a.z, b2.z, fmaf(a.w, b3.z, acc[r][2]))));
            acc[r][3] = fmaf(a.x, b0.w, fmaf(a.y, b1.w, fmaf(a.z, b2.w, fmaf(a.w, b3.w, acc[r][3]))));
        }
    }
#pragma unroll
    for (int r = 0; r < 4; ++r) {
        int row = m0 + g * 4 + r;
        if (row < N_NODES) {
            uint2 v; v.x = pack2(acc[r][0], acc[r][1]); v.y = pack2(acc[r][2], acc[r][3]);
            C[(size_t)row * 32 + l] = v;
        }
    }
    int h = l >> 3, f0 = 4 * (l & 7);
    float al0 = aux[h * 64 + f0], al1 = aux[h * 64 + f0 + 1], al2 = aux[h * 64 + f0 + 2], al3 = aux[h * 64 + f0 + 3];
    float ar0 = aux[h * 64 + 32 + f0], ar1 = aux[h * 64 + 32 + f0 + 1], ar2 = aux[h * 64 + 32 + f0 + 2], ar3 = aux[h * 64 + 32 + f0 + 3];
#pragma unroll
    for (int r = 0; r < 4; ++r) {
        float pl = acc[r][0] * al0 + acc[r][1] * al1 + acc[r][2] * al2 + acc[r][3] * al3;
        float pr = acc[r][0] * ar0 + acc[r][1] * ar1 + acc[r][2] * ar2 + acc[r][3] * ar3;
#pragma unroll
        for (int mask = 4; mask; mask >>= 1) { pl += __shfl_xor(pl, mask); pr += __shfl_xor(pr, mask); }
        if ((l & 7) == 0) {
            int row = m0 + g * 4 + r;
            if (row < N_NODES) { es[row * 4 + h] = pl; ed[row * 4 + h] = pr; }
        }
    }
}

__global__ void k_scan1(const int* __restrict__ deg, int* __restrict__ off, int* __restrict__ blksum) {
    __shared__ int sh[1024];
    int b = blockIdx.x;
    int i = b * 1024 + threadIdx.x;
    int v = (i < N_NODES) ? deg[i] : 0;
    sh[threadIdx.x] = v;
    __syncthreads();
    for (int ofs = 1; ofs < 1024; ofs <<= 1) {
        int t = (threadIdx.x >= ofs) ? sh[threadIdx.x - ofs] : 0;
        __syncthreads();
        sh[threadIdx.x] += t;
        __syncthreads();
    }
    if (i < N_NODES) off[i] = sh[threadIdx.x] - v;
    if (threadIdx.x == 1023) blksum[b] = sh[1023];
}

__global__ void k_scan2(const int* __restrict__ blksum, int* __restrict__ blkoff, int* __restrict__ off) {
    int l = threadIdx.x & 63;
    int v = (l < NBLK) ? blksum[l] : 0;
    int incl = v;
    for (int ofs = 1; ofs < 64; ofs <<= 1) {
        int t = __shfl_up(incl, ofs);
        if (l >= ofs) incl += t;
    }
    if (l < NBLK) blkoff[l] = incl - v;
    if (l == 63) off[N_NODES] = incl;
}

__global__ void k_scan3(int* __restrict__ off, const int* __restrict__ blkoff) {
    int i = blockIdx.x * blockDim.x + threadIdx.x;
    if (i >= N_NODES) return;
    off[i] += blkoff[i >> 10];
}

__global__ void k_scatter2(const int* __restrict__ ei, const int* __restrict__ off,
                           const unsigned short* __restrict__ rank,
                           unsigned short* __restrict__ srcs) {
    int t = blockIdx.x * blockDim.x + threadIdx.x;
    int e0 = 4 * t;
    if (e0 >= E_TOT) return;
    int row[4], col[4], rk[4];
    if (e0 + 3 < E_TOT && e0 + 3 < E_RAW) {
        int4 r4 = ((const int4*)ei)[t];
        int4 c4 = ((const int4*)(ei + E_RAW))[t];
        ushort4 k4 = ((const ushort4*)rank)[t];
        row[0] = r4.x; row[1] = r4.y; row[2] = r4.z; row[3] = r4.w;
        col[0] = c4.x; col[1] = c4.y; col[2] = c4.z; col[3] = c4.w;
        rk[0] = k4.x; rk[1] = k4.y; rk[2] = k4.z; rk[3] = k4.w;
    } else {
#pragma unroll
        for (int i = 0; i < 4; ++i) {
            int e = e0 + i;
            if (e < E_RAW) { row[i] = ei[e]; col[i] = ei[E_RAW + e]; }
            else { row[i] = e - E_RAW; col[i] = row[i]; }
            rk[i] = (e < E_TOT) ? rank[e] : 0;
        }
    }
#pragma unroll
    for (int i = 0; i < 4; ++i)
        if (e0 + i < E_TOT) srcs[off[col[i]] + rk[i]] = (unsigned short)row[i];
}

// ---------------- GEMM 2: h2 = out1(bf16) @ W2, 256 thr, MT=64, attn2 epilogue ----------------
__global__ void k_gemm2(const unsigned* __restrict__ Ab, const float* __restrict__ B,
                        const float* __restrict__ aux, uint2* __restrict__ C,
                        float* __restrict__ es, float* __restrict__ ed) {
    constexpr int K = 128, MT = 64;
    __shared__ float As[MT * K];   // 32 KB
    int m0 = blockIdx.x * MT;
    int t = threadIdx.x, g = t >> 4, l = t & 15;   // 16 groups x 4 rows
    int rows = min(MT, N_NODES - m0);
    const uint2* A2 = (const uint2*)(Ab + (size_t)m0 * 64);   // row = 32 uint2
    float4* S4 = (float4*)As;
    for (int i = t; i < rows * 32; i += 256) {
        uint2 u = A2[i];
        float4 f; f.x = bflo(u.x); f.y = bfhi(u.x); f.z = bflo(u.y); f.w = bfhi(u.y);
        S4[i] = f;
    }
    __syncthreads();
    float acc[4][4];
#pragma unroll
    for (int r = 0; r < 4; ++r)
#pragma unroll
        for (int c = 0; c < 4; ++c) acc[r][c] = 0.f;
    const float4* B4 = (const float4*)B;   // row k = 16 float4
    for (int kk = 0; kk < K / 4; ++kk) {
        float4 b0 = B4[(4 * kk + 0) * 16 + l];
        float4 b1 = B4[(4 * kk + 1) * 16 + l];
        float4 b2 = B4[(4 * kk + 2) * 16 + l];
        float4 b3 = B4[(4 * kk + 3) * 16 + l];
#pragma unroll
        for (int r = 0; r < 4; ++r) {
            float4 a = ((const float4*)(As + (g * 4 + r) * K))[kk];
            acc[r][0] = fmaf(a.x, b0.x, fmaf(a.y, b1.x, fmaf(a.z, b2.x, fmaf(a.w, b3.x, acc[r][0]))));
            acc[r][1] = fmaf(a.x, b0.y, fmaf(a.y, b1.y, fmaf(a.z, b2.y, fmaf(a.w, b3.y, acc[r][1]))));
            acc[r][2] = fmaf(a.x, b0.z, fmaf(a.y, b1.z, fmaf(a.z, b2.z, fmaf(a.w, b3.z, acc[r][2]))));
            acc[r][3] = fmaf(a.x, b0.w, fmaf(a.y, b1.w, fmaf(a.z, b2.w, fmaf(a.w, b3.w, acc[r][3]))));
        }
    }
    float al0 = aux[4 * l], al1 = aux[4 * l + 1], al2 = aux[4 * l + 2], al3 = aux[4 * l + 3];
    float ar0 = aux[64 + 4 * l], ar1 = aux[64 + 4 * l + 1], ar2 = aux[64 + 4 * l + 2], ar3 = aux[64 + 4 * l + 3];
#pragma unroll
    for (int r = 0; r < 4; ++r) {
        int row = m0 + g * 4 + r;
        float pl = acc[r][0] * al0 + acc[r][1] * al1 + acc[r][2] * al2 + acc[r][3] * al3;
        float pr = acc[r][0] * ar0 + acc[r][1] * ar1 + acc[r][2] * ar2 + acc[r][3] * ar3;
#pragma unroll
        for (int mask = 8; mask; mask >>= 1) { pl += __shfl_xor(pl, mask); pr += __shfl_xor(pr, mask); }
        if (row < N_NODES) {
            uint2 v; v.x = pack2(acc[r][0], acc[r][1]); v.y = pack2(acc[r][2], acc[r][3]);
            C[(size_t)row * 16 + l] = v;
            if (l == 0) { es[row] = pl; ed[row] = pr; }
        }
    }
}

// ---------------- GEMM 3 (head): out = h2agg @ headW + b, 256 thr, MT=64 ----------------
__global__ void k_gemm3(const float* __restrict__ A, const float* __restrict__ B,
                        const float* __restrict__ bias, float4* __restrict__ C) {
    constexpr int K = 64, MT = 64;
    __shared__ float As[MT * K];   // 16 KB
    int m0 = blockIdx.x * MT;
    int t = threadIdx.x, g = t >> 4, l = t & 15;
    int rows = min(MT, N_NODES - m0);
    const float4* A4 = (const float4*)(A + (size_t)m0 * K);
    float4* S4 = (float4*)As;
    for (int i = t; i < rows * 16; i += 256) S4[i] = A4[i];
    __syncthreads();
    float acc[4][4];
#pragma unroll
    for (int r = 0; r < 4; ++r)
#pragma unroll
        for (int c = 0; c < 4; ++c) acc[r][c] = 0.f;
    const float4* B4 = (const float4*)B;   // row k = 16 float4
    for (int kk = 0; kk < K / 4; ++kk) {
        float4 b0 = B4[(4 * kk + 0) * 16 + l];
        float4 b1 = B4[(4 * kk + 1) * 16 + l];
        float4 b2 = B4[(4 * kk + 2) * 16 + l];
        float4 b3 = B4[(4 * kk + 3) * 16 + l];
#pragma unroll
        for (int r = 0; r < 4; ++r) {
            float4 a = ((const float4*)(As + (g * 4 + r) * K))[kk];
            acc[r][0] = fmaf(a.x, b0.x, fmaf(a.y, b1.x, fmaf(a.z, b2.x, fmaf(a.w, b3.x, acc[r][0]))));
            acc[r][1] = fmaf(a.x, b0.y, fmaf(a.y, b1.y, fmaf(a.z, b2.y, fmaf(a.w, b3.y, acc[r][1]))));
            acc[r][2] = fmaf(a.x, b0.z, fmaf(a.y, b1.z, fmaf(a.z, b2.z, fmaf(a.w, b3.z, acc[r][2]))));
            acc[r][3] = fmaf(a.x, b0.w, fmaf(a.y, b1.w, fmaf(a.z, b2.w, fmaf(a.w, b3.w, acc[r][3]))));
        }
    }
    float4 bv = ((const float4*)bias)[l];
#pragma unroll
    for (int r = 0; r < 4; ++r) {
        int row = m0 + g * 4 + r;
        if (row < N_NODES) {
            float4 v;
            v.x = acc[r][0] + bv.x; v.y = acc[r][1] + bv.y;
            v.z = acc[r][2] + bv.z; v.w = acc[r][3] + bv.w;
            C[(size_t)row * 16 + l] = v;
        }
    }
}

// ---------------- layer-1 fused softmax+aggregate: one wave per node ----------------
__global__ void k_agg1(const unsigned* __restrict__ h1b, const float* __restrict__ es,
                       const float* __restrict__ ed, const int* __restrict__ off,
                       const unsigned short* __restrict__ srcs, unsigned* __restrict__ out1b) {
    int n = blockIdx.x * (blockDim.x >> 6) + (threadIdx.x >> 6);
    int lane = threadIdx.x & 63;
    if (n >= N_NODES) return;
    int myh = lane & 3;
    float edh = ed[n * 4 + myh];
    int hc = lane >> 4;
    int s = off[n], e = off[n + 1];
    int jj = lane >> 2;
    float ax = 0.f, ay = 0.f, psum = 0.f;
    for (int base = s; base < e; base += 16) {
        int cnt = e - base;
        int srcj = 0;
        float w = 0.f;
        if (jj < cnt) {
            srcj = srcs[base + jj];
            w = __expf(lrelu(es[srcj * 4 + myh] + edh));
        }
        psum += w;
        unsigned pv[16];
        float wv[16];
#pragma unroll
        for (int j2 = 0; j2 < 16; ++j2) {
            int src = __shfl(srcj, j2 * 4);
            wv[j2] = __shfl(w, j2 * 4 + hc);
            pv[j2] = h1b[(size_t)src * 64 + lane];
        }
#pragma unroll
        for (int j2 = 0; j2 < 16; ++j2) {
            ax = fmaf(bflo(pv[j2]), wv[j2], ax);
            ay = fmaf(bfhi(pv[j2]), wv[j2], ay);
        }
    }
#pragma unroll
    for (int mask = 4; mask <= 32; mask <<= 1) psum += __shfl_xor(psum, mask);
    float inv = 1.f / __shfl(psum, hc);
    // ReLU + bf16 pack (out1 consumed only by gemm2)
    out1b[(size_t)n * 64 + lane] = pack2(fmaxf(ax * inv, 0.f), fmaxf(ay * inv, 0.f));
}

// ---------------- layer-2 fused softmax+aggregate: half-wave per node ----------------
__global__ void k_agg2(const unsigned* __restrict__ h2b, const float* __restrict__ es,
                       const float* __restrict__ ed, const int* __restrict__ off,
                       const unsigned short* __restrict__ srcs, float* __restrict__ outv) {
    int n = blockIdx.x * (blockDim.x >> 5) + (threadIdx.x >> 5);
    int l = threadIdx.x & 31;
    int hb = threadIdx.x & 32;
    if (n >= N_NODES) return;
    float edv = ed[n];
    int s = off[n], e = off[n + 1];
    const uint2* gp = (const uint2*)h2b;
    int l16 = l & 15;
    int sb0 = (l >> 4) * 2;
    float a0 = 0.f, a1 = 0.f, a2 = 0.f, a3 = 0.f, psum = 0.f;
    for (int base = s; base < e; base += 32) {
        int cnt = e - base;
        int srcj = 0;
        float w = 0.f;
        if (l < cnt) {
            srcj = srcs[base + l];
            w = __expf(lrelu(es[srcj] + edv));
        }
        psum += w;
#pragma unroll
        for (int sub = 0; sub < 2; ++sub) {
            uint2 pv[8];
            float wv[8];
#pragma unroll
            for (int j = 0; j < 8; ++j) {
                int lsrc = hb + (sb0 + sub) * 8 + j;
                int src = __shfl(srcj, lsrc);
                wv[j] = __shfl(w, lsrc);
                pv[j] = gp[(size_t)src * 16 + l16];
            }
#pragma unroll
            for (int j = 0; j < 8; ++j) {
                a0 = fmaf(bflo(pv[j].x), wv[j], a0);
                a1 = fmaf(bfhi(pv[j].x), wv[j], a1);
                a2 = fmaf(bflo(pv[j].y), wv[j], a2);
                a3 = fmaf(bfhi(pv[j].y), wv[j], a3);
            }
        }
    }
#pragma unroll
    for (int mask = 1; mask <= 16; mask <<= 1) psum += __shfl_xor(psum, mask);
    float inv = 1.f / psum;
    a0 += __shfl_xor(a0, 16); a1 += __shfl_xor(a1, 16);
    a2 += __shfl_xor(a2, 16); a3 += __shfl_xor(a3, 16);
    if (l < 16) {
        float4 o;
        o.x = a0 * inv; o.y = a1 * inv; o.z = a2 * inv; o.w = a3 * inv;
        ((float4*)outv)[(size_t)n * 16 + l16] = o;
    }
}

extern "C" void kernel_launch(void* const* d_in, const int* in_sizes, int n_in,
                              void* d_out, int out_size, void* d_ws, size_t ws_size,
                              hipStream_t stream) {
    const float* x     = (const float*)d_in[0];
    const int*   ei    = (const int*)d_in[1];
    const float* W1    = (const float*)d_in[2];
    const float* attn1 = (const float*)d_in[3];
    const float* W2    = (const float*)d_in[4];
    const float* attn2 = (const float*)d_in[5];
    const float* headW = (const float*)d_in[6];
    const float* headb = (const float*)d_in[7];
    float* out = (float*)d_out;

    char* ws = (char*)d_ws;
    size_t o = 0;
    auto alloc = [&](size_t bytes) -> void* {
        o = (o + 255) & ~(size_t)255;
        void* p = ws + o;
        o += bytes;
        return p;
    };
    unsigned*       h1b    = (unsigned*)alloc((size_t)N_NODES * 128 * 2);
    unsigned*       out1b  = (unsigned*)alloc((size_t)N_NODES * 128 * 2);
    unsigned*       h2b    = (unsigned*)alloc((size_t)N_NODES * 64 * 2);
    float*          h2agg  = (float*)alloc((size_t)N_NODES * 64 * 4);
    float*          e1s    = (float*)alloc((size_t)N_NODES * 4 * 4);
    float*          e1d    = (float*)alloc((size_t)N_NODES * 4 * 4);
    float*          e2s    = (float*)alloc((size_t)N_NODES * 4);
    float*          e2d    = (float*)alloc((size_t)N_NODES * 4);
    int*            deg    = (int*)alloc((size_t)N_NODES * 4);
    int*            off    = (int*)alloc((size_t)(N_NODES + 1) * 4);
    unsigned short* rank   = (unsigned short*)alloc((size_t)E_TOT * 2);
    unsigned short* srcs   = (unsigned short*)alloc((size_t)E_TOT * 2);
    int*            blksum = (int*)alloc((size_t)NBLK * 4);
    int*            blkoff = (int*)alloc((size_t)NBLK * 4);

    // fused: gemm1 (+attn1 epilogue) || deg_rank histogram (interleaved blocks)
    (void)hipMemsetAsync(deg, 0, (size_t)N_NODES * 4, stream);
    k_gemm1_deg<<<G1_BLOCKS + G2_BLOCKS, 256, 0, stream>>>(
        x, W1, attn1, (uint2*)h1b, e1s, e1d, ei, deg, rank);

    // CSR finalize
    k_scan1<<<NBLK, 1024, 0, stream>>>(deg, off, blksum);
    k_scan2<<<1, 64, 0, stream>>>(blksum, blkoff, off);
    k_scan3<<<(N_NODES + 255) / 256, 256, 0, stream>>>(off, blkoff);
    k_scatter2<<<(E_TOT / 4 + 255) / 256, 256, 0, stream>>>(ei, off, rank, srcs);

    // layer 1 aggregate (bf16 out)
    k_agg1<<<N_NODES / 4, 256, 0, stream>>>(h1b, e1s, e1d, off, srcs, out1b);

    // layer 2
    k_gemm2<<<(N_NODES + 63) / 64, 256, 0, stream>>>(out1b, W2, attn2, (uint2*)h2b, e2s, e2d);
    k_agg2<<<N_NODES / 8, 256, 0, stream>>>(h2b, e2s, e2d, off, srcs, h2agg);

    // head
    k_gemm3<<<(N_NODES + 63) / 64, 256, 0, stream>>>(h2agg, headW, headb, (float4*)out);
}